// Round 1
// baseline (1266.564 us; speedup 1.0000x reference)
//
#include <hip/hip_runtime.h>
#include <cstdint>
#include <cstddef>

// RobustGCN forward on MI355X.
// Pipeline:
//   1. graph prep: degree count (atomics) -> dis=deg^-0.5, di=deg^-1; scan -> CSR
//   2. GEMM1 (f16 MFMA): Hcat = [elu(x@Wm0+bm0) | relu(x@Wv0+bv0)]  (N x 512)
//   3. GEMM2 (f16 MFMA, block-diag W): m2 = elu(.@Wm1+bm1), v2 = relu(.@Wv1+bv1)+1e-6
//   4. attn elementwise (in place): Mm = m2*exp(-v2), Mv = v2*exp(-2*v2)
//   5. fused SpMM (CSR, wave per node, lane per class) + sample*sqrt(var) + log_softmax

typedef _Float16 h8 __attribute__((ext_vector_type(8)));
typedef float f32x4 __attribute__((ext_vector_type(4)));

static __device__ __forceinline__ float elu_f(float z) {
  return z > 0.f ? z : expm1f(z);
}

// ---------------- graph prep ----------------
__global__ void deg_count_k(const int* __restrict__ esrc, int E, int* __restrict__ cnt) {
  int e = blockIdx.x * 256 + threadIdx.x;
  if (e < E) atomicAdd(&cnt[esrc[e]], 1);
}

__global__ void deg_fin_k(const int* __restrict__ cnt, float* __restrict__ dis,
                          float* __restrict__ di, int n) {
  int v = blockIdx.x * 256 + threadIdx.x;
  if (v < n) {
    float d = (float)(cnt[v] + 1);  // +1 self loop
    dis[v] = rsqrtf(d);
    di[v] = 1.f / d;
  }
}

__global__ void scan1_k(const int* __restrict__ cnt, int* __restrict__ excl,
                        int* __restrict__ bsum, int n) {
  __shared__ int sh[256];
  int t = threadIdx.x, idx = blockIdx.x * 256 + t;
  int v = (idx < n) ? cnt[idx] : 0;
  sh[t] = v;
  __syncthreads();
  for (int off = 1; off < 256; off <<= 1) {
    int add = (t >= off) ? sh[t - off] : 0;
    __syncthreads();
    sh[t] += add;
    __syncthreads();
  }
  if (idx < n) excl[idx] = sh[t] - v;
  if (t == 255) bsum[blockIdx.x] = sh[255];
}

__global__ void scan2_k(const int* __restrict__ bsum, int* __restrict__ boff, int nb) {
  __shared__ int sh[512];
  int t = threadIdx.x;
  int v = (t < nb) ? bsum[t] : 0;
  sh[t] = v;
  __syncthreads();
  for (int off = 1; off < 512; off <<= 1) {
    int add = (t >= off) ? sh[t - off] : 0;
    __syncthreads();
    sh[t] += add;
    __syncthreads();
  }
  if (t < nb) boff[t] = sh[t] - v;
}

__global__ void scan3_k(int* __restrict__ excl, const int* __restrict__ boff,
                        int* __restrict__ cursor, int n) {
  int idx = blockIdx.x * 256 + threadIdx.x;
  if (idx < n) {
    int v = excl[idx] + boff[blockIdx.x];
    excl[idx] = v;
    cursor[idx] = v;
  }
}

__global__ void scatter_k(const int* __restrict__ esrc, const int* __restrict__ edst,
                          int* __restrict__ cursor, int* __restrict__ csr, int E) {
  int e = blockIdx.x * 256 + threadIdx.x;
  if (e < E) {
    int s = esrc[e];
    int pos = atomicAdd(&cursor[s], 1);
    csr[pos] = edst[e];
  }
}

// ---------------- weight prep: transpose + f16 + fuse ----------------
// W1t[n][k], n in [0,512): n<256 -> Wm0[:,n], else Wv0[:,n-256]
// W2t[n][k], n in [0,128): block-diag of Wm1 (k<256) and Wv1 (k>=256)
__global__ void prep_w_k(const float* __restrict__ Wm0, const float* __restrict__ Wv0,
                         const float* __restrict__ Wm1, const float* __restrict__ Wv1,
                         _Float16* __restrict__ W1t, _Float16* __restrict__ W2t) {
  int idx = blockIdx.x * 256 + threadIdx.x;
  if (idx < 512 * 512) {
    int n = idx >> 9, k = idx & 511;
    float v = (n < 256) ? Wm0[k * 256 + n] : Wv0[k * 256 + (n - 256)];
    W1t[idx] = (_Float16)v;
  }
  if (idx < 128 * 512) {
    int n = idx >> 9, k = idx & 511;
    float v = 0.f;
    if (n < 64) { if (k < 256) v = Wm1[k * 64 + n]; }
    else        { if (k >= 256) v = Wv1[(k - 256) * 64 + (n - 64)]; }
    W2t[idx] = (_Float16)v;
  }
}

// ---------------- MFMA GEMM: C = A(MxK,f32|f16) @ Bt(n-major,f16)^T ----------------
// BM=BN=128, BK=32, 256 threads (4 waves, 2x2), each wave 4x4 of 16x16x32 MFMA.
// LDS tiles stored [row][k] with stride 40 halves (pad -> <=2-way bank conflict = free).
// MODE 0: Hcat epilogue (elu cols<256, relu else), out stride 512
// MODE 1: out0=elu(+bm1) cols<64, out1=relu(+bv1)+1e-6 cols>=64, stride 64
template <typename AT, int MODE, int NT>
__global__ __launch_bounds__(256) void gemm_k(
    const AT* __restrict__ A, const _Float16* __restrict__ Bt,
    const float* __restrict__ b0, const float* __restrict__ b1,
    _Float16* __restrict__ out0, _Float16* __restrict__ out1,
    int M, int K) {
  __shared__ _Float16 As[128 * 40];
  __shared__ _Float16 Bs[128 * 40];
  const int bid = blockIdx.x;
  const int mt = bid / NT, nt = bid % NT;   // nt inner -> A-tile reuse in L2/L3
  const int m0 = mt * 128, n0 = nt * 128;
  const int t = threadIdx.x;
  const int lane = t & 63;
  const int wave = t >> 6;
  const int wm = wave >> 1, wn = wave & 1;
  const int lr = lane & 15, quad = lane >> 4;

  f32x4 acc[4][4] = {};

  for (int kt = 0; kt < K; kt += 32) {
#pragma unroll
    for (int i = 0; i < 2; i++) {
      int c = t + i * 256;              // 512 chunks of 8 halves = 128x32 tile
      int row = c >> 2, kc = (c & 3) * 8;
      int gr = m0 + row;
      if (gr > M - 1) gr = M - 1;       // clamp tail; stores are guarded
      h8 hv;
      if constexpr (sizeof(AT) == 4) {  // f32 source: convert during staging
        const float* srcf = (const float*)A + (size_t)gr * K + kt + kc;
        float4 f0 = ((const float4*)srcf)[0];
        float4 f1 = ((const float4*)srcf)[1];
        hv = h8{(_Float16)f0.x, (_Float16)f0.y, (_Float16)f0.z, (_Float16)f0.w,
                (_Float16)f1.x, (_Float16)f1.y, (_Float16)f1.z, (_Float16)f1.w};
      } else {
        hv = *(const h8*)((const _Float16*)A + (size_t)gr * K + kt + kc);
      }
      *(h8*)&As[row * 40 + kc] = hv;
      *(h8*)&Bs[row * 40 + kc] =
          *(const h8*)(Bt + (size_t)(n0 + row) * K + kt + kc);
    }
    __syncthreads();
    h8 af[4], bf[4];
#pragma unroll
    for (int i = 0; i < 4; i++)
      af[i] = *(h8*)&As[(wm * 64 + i * 16 + lr) * 40 + quad * 8];
#pragma unroll
    for (int j = 0; j < 4; j++)
      bf[j] = *(h8*)&Bs[(wn * 64 + j * 16 + lr) * 40 + quad * 8];
#pragma unroll
    for (int i = 0; i < 4; i++)
#pragma unroll
      for (int j = 0; j < 4; j++)
        acc[i][j] = __builtin_amdgcn_mfma_f32_16x16x32_f16(af[i], bf[j], acc[i][j], 0, 0, 0);
    __syncthreads();
  }

  // epilogue: D row = quad*4+reg, col = lane&15 (m89-verified mapping)
#pragma unroll
  for (int j = 0; j < 4; j++) {
    int gc = n0 + wn * 64 + j * 16 + lr;
    float bj;
    if (MODE == 0) bj = (gc < 256) ? b0[gc] : b1[gc - 256];
    else           bj = (gc < 64) ? b0[gc] : b1[gc - 64];
#pragma unroll
    for (int i = 0; i < 4; i++) {
#pragma unroll
      for (int r = 0; r < 4; r++) {
        int gr = m0 + wm * 64 + i * 16 + quad * 4 + r;
        if (gr < M) {
          float z = acc[i][j][r] + bj;
          if (MODE == 0) {
            float v = (gc < 256) ? elu_f(z) : fmaxf(z, 0.f);
            out0[(size_t)gr * 512 + gc] = (_Float16)v;
          } else {
            if (gc < 64) {
              out0[(size_t)gr * 64 + gc] = (_Float16)elu_f(z);
            } else {
              out1[(size_t)gr * 64 + (gc - 64)] = (_Float16)(fmaxf(z, 0.f) + 1e-6f);
            }
          }
        }
      }
    }
  }
}

// ---------------- attn elementwise (in place) ----------------
__global__ void attn_k(_Float16* __restrict__ Rm, _Float16* __restrict__ Rv, int total) {
  int idx = blockIdx.x * 256 + threadIdx.x;
  if (idx < total) {
    float m = (float)Rm[idx], v = (float)Rv[idx];
    float a = __expf(-v);
    Rm[idx] = (_Float16)(m * a);   // mean*attn
    Rv[idx] = (_Float16)(v * a * a); // var*attn^2
  }
}

// ---------------- fused dual SpMM + reparam + log_softmax ----------------
// wave per node row, lane = class (CLS=64).
// out_mean[r] = dis[r]*(sum_d dis[d]*Mm[d] + dis[r]*Mm[r])
// out_var [r] = di [r]*(sum_d di [d]*Mv[d] + di [r]*Mv[r])
__global__ __launch_bounds__(256) void spmm_final_k(
    const _Float16* __restrict__ Mm, const _Float16* __restrict__ Mv,
    const float* __restrict__ dis, const float* __restrict__ di,
    const int* __restrict__ row_start, const int* __restrict__ cnt,
    const int* __restrict__ csr, const float* __restrict__ sample,
    float* __restrict__ out, int n) {
  int wid = threadIdx.x >> 6, lane = threadIdx.x & 63;
  int r = blockIdx.x * 4 + wid;
  if (r >= n) return;
  float dsr = dis[r], dir = di[r];
  float Sm = dsr * (float)Mm[(size_t)r * 64 + lane];  // self loop
  float Sv = dir * (float)Mv[(size_t)r * 64 + lane];
  int start = row_start[r], c = cnt[r];
  for (int j = 0; j < c; j++) {
    int d = csr[start + j];
    Sm += dis[d] * (float)Mm[(size_t)d * 64 + lane];
    Sv += di[d] * (float)Mv[(size_t)d * 64 + lane];
  }
  float mean = dsr * Sm;
  float var = dir * Sv;
  float o = mean + sample[(size_t)r * 64 + lane] * sqrtf(var);
  // log_softmax across 64 lanes
  float mx = o;
#pragma unroll
  for (int off = 32; off; off >>= 1) mx = fmaxf(mx, __shfl_xor(mx, off, 64));
  float ex = __expf(o - mx);
  float s = ex;
#pragma unroll
  for (int off = 32; off; off >>= 1) s += __shfl_xor(s, off, 64);
  out[(size_t)r * 64 + lane] = o - mx - logf(s);
}

// ---------------- launch ----------------
extern "C" void kernel_launch(void* const* d_in, const int* in_sizes, int n_in,
                              void* d_out, int out_size, void* d_ws, size_t ws_size,
                              hipStream_t stream) {
  (void)n_in; (void)out_size; (void)ws_size;
  const float* x    = (const float*)d_in[0];
  const float* Wm0  = (const float*)d_in[1];
  const float* bm0  = (const float*)d_in[2];
  const float* Wv0  = (const float*)d_in[3];
  const float* bv0  = (const float*)d_in[4];
  const float* Wm1  = (const float*)d_in[5];
  const float* bm1  = (const float*)d_in[6];
  const float* Wv1  = (const float*)d_in[7];
  const float* bv1  = (const float*)d_in[8];
  const float* sample = (const float*)d_in[9];
  const int* esrc   = (const int*)d_in[10];
  const int* edst   = (const int*)d_in[11];
  float* out = (float*)d_out;

  const int N = in_sizes[0] / 512;
  const int E = in_sizes[10];

  uint8_t* p = (uint8_t*)d_ws;
  size_t off = 0;
  auto alloc = [&](size_t bytes) -> void* {
    void* r = p + off;
    off += (bytes + 255) & ~(size_t)255;
    return r;
  };
  _Float16* W1t  = (_Float16*)alloc((size_t)512 * 512 * 2);
  _Float16* W2t  = (_Float16*)alloc((size_t)128 * 512 * 2);
  _Float16* Hcat = (_Float16*)alloc((size_t)N * 512 * 2);
  _Float16* Rm   = (_Float16*)alloc((size_t)N * 64 * 2);
  _Float16* Rv   = (_Float16*)alloc((size_t)N * 64 * 2);
  int*   cnt    = (int*)alloc((size_t)N * 4);
  float* dis    = (float*)alloc((size_t)N * 4);
  float* di     = (float*)alloc((size_t)N * 4);
  int*   rs     = (int*)alloc((size_t)N * 4);
  int*   cursor = (int*)alloc((size_t)N * 4);
  int*   bsum   = (int*)alloc(2048);
  int*   boff   = (int*)alloc(2048);
  int*   csr    = (int*)alloc((size_t)E * 4);

  hipMemsetAsync(cnt, 0, (size_t)N * 4, stream);

  const int nbN = (N + 255) / 256;
  const int nbE = (E + 255) / 256;

  prep_w_k<<<(512 * 512 + 255) / 256, 256, 0, stream>>>(Wm0, Wv0, Wm1, Wv1, W1t, W2t);
  deg_count_k<<<nbE, 256, 0, stream>>>(esrc, E, cnt);
  deg_fin_k<<<nbN, 256, 0, stream>>>(cnt, dis, di, N);
  scan1_k<<<nbN, 256, 0, stream>>>(cnt, rs, bsum, N);
  scan2_k<<<1, 512, 0, stream>>>(bsum, boff, nbN);
  scan3_k<<<nbN, 256, 0, stream>>>(rs, boff, cursor, N);
  scatter_k<<<nbE, 256, 0, stream>>>(esrc, edst, cursor, csr, E);

  const int mtiles = (N + 127) / 128;
  gemm_k<float, 0, 4><<<mtiles * 4, 256, 0, stream>>>(x, W1t, bm0, bv0, Hcat, nullptr, N, 512);
  gemm_k<_Float16, 1, 1><<<mtiles, 256, 0, stream>>>(Hcat, W2t, bm1, bv1, Rm, Rv, N, 512);
  attn_k<<<(N * 64 + 255) / 256, 256, 0, stream>>>(Rm, Rv, N * 64);
  spmm_final_k<<<(N + 3) / 4, 256, 0, stream>>>(Rm, Rv, dis, di, rs, cnt, csr, sample, out, N);
}

// Round 2
// 1053.839 us; speedup vs baseline: 1.2019x; 1.2019x over previous
//
#include <hip/hip_runtime.h>
#include <cstdint>
#include <cstddef>

// RobustGCN forward on MI355X.
// Pipeline:
//   1. graph prep: degree count (atomics) -> dd=(deg^-0.5, deg^-1); padded scan -> CSR
//   2. GEMM1 (f16 MFMA): Hcat = [elu(x@Wm0+bm0) | relu(x@Wv0+bv0)]  (N x 512)
//   3. GEMM2 (f16 MFMA, block-diag W) with FUSED attention epilogue:
//        m = elu(.@Wm1+bm1); v = relu(.@Wv1+bv1)+1e-6; a=exp(-v)
//        Mcat[r][c] = pack_h2(m*a, v*a*a)        (one uint per (node,class))
//   4. fused dual SpMM (CSR, wave/node, lane/class, 4-edge int4 batches)
//      + sample*sqrt(var) + log_softmax

typedef _Float16 h8 __attribute__((ext_vector_type(8)));
typedef _Float16 h2 __attribute__((ext_vector_type(2)));
typedef float f32x4 __attribute__((ext_vector_type(4)));
typedef unsigned int uint32;

static __device__ __forceinline__ float elu_f(float z) {
  return z > 0.f ? z : expm1f(z);
}

// ---------------- graph prep ----------------
__global__ void deg_count_k(const int* __restrict__ esrc, int E, int* __restrict__ cnt) {
  int e = blockIdx.x * 256 + threadIdx.x;
  if (e < E) atomicAdd(&cnt[esrc[e]], 1);
}

__global__ void deg_fin_k(const int* __restrict__ cnt, float2* __restrict__ dd, int n) {
  int v = blockIdx.x * 256 + threadIdx.x;
  if (v < n) {
    float d = (float)(cnt[v] + 1);  // +1 self loop
    dd[v] = make_float2(rsqrtf(d), 1.f / d);
  }
}

// exclusive scan of PADDED counts ((cnt+3)&~3) so every CSR row start is 16B-aligned
__global__ void scan1_k(const int* __restrict__ cnt, int* __restrict__ excl,
                        int* __restrict__ bsum, int n) {
  __shared__ int sh[256];
  int t = threadIdx.x, idx = blockIdx.x * 256 + t;
  int v = (idx < n) ? ((cnt[idx] + 3) & ~3) : 0;
  sh[t] = v;
  __syncthreads();
  for (int off = 1; off < 256; off <<= 1) {
    int add = (t >= off) ? sh[t - off] : 0;
    __syncthreads();
    sh[t] += add;
    __syncthreads();
  }
  if (idx < n) excl[idx] = sh[t] - v;
  if (t == 255) bsum[blockIdx.x] = sh[255];
}

__global__ void scan2_k(const int* __restrict__ bsum, int* __restrict__ boff, int nb) {
  __shared__ int sh[512];
  int t = threadIdx.x;
  int v = (t < nb) ? bsum[t] : 0;
  sh[t] = v;
  __syncthreads();
  for (int off = 1; off < 512; off <<= 1) {
    int add = (t >= off) ? sh[t - off] : 0;
    __syncthreads();
    sh[t] += add;
    __syncthreads();
  }
  if (t < nb) boff[t] = sh[t] - v;
}

__global__ void scan3_k(int* __restrict__ excl, const int* __restrict__ boff,
                        int* __restrict__ cursor, int n) {
  int idx = blockIdx.x * 256 + threadIdx.x;
  if (idx < n) {
    int v = excl[idx] + boff[blockIdx.x];
    excl[idx] = v;
    cursor[idx] = v;
  }
}

__global__ void scatter_k(const int* __restrict__ esrc, const int* __restrict__ edst,
                          int* __restrict__ cursor, int* __restrict__ csr, int E) {
  int e = blockIdx.x * 256 + threadIdx.x;
  if (e < E) {
    int s = esrc[e];
    int pos = atomicAdd(&cursor[s], 1);
    csr[pos] = edst[e];
  }
}

// ---------------- weight prep: transpose + f16 + fuse ----------------
__global__ void prep_w_k(const float* __restrict__ Wm0, const float* __restrict__ Wv0,
                         const float* __restrict__ Wm1, const float* __restrict__ Wv1,
                         _Float16* __restrict__ W1t, _Float16* __restrict__ W2t) {
  int idx = blockIdx.x * 256 + threadIdx.x;
  if (idx < 512 * 512) {
    int n = idx >> 9, k = idx & 511;
    float v = (n < 256) ? Wm0[k * 256 + n] : Wv0[k * 256 + (n - 256)];
    W1t[idx] = (_Float16)v;
  }
  if (idx < 128 * 512) {
    int n = idx >> 9, k = idx & 511;
    float v = 0.f;
    if (n < 64) { if (k < 256) v = Wm1[k * 64 + n]; }
    else        { if (k >= 256) v = Wv1[(k - 256) * 64 + (n - 64)]; }
    W2t[idx] = (_Float16)v;
  }
}

// ---------------- GEMM1: Hcat = act(x @ W1t^T + b) ----------------
// BM=BN=128, BK=32, 256 threads (4 waves 2x2), wave = 4x4 of 16x16x32 MFMA.
__global__ __launch_bounds__(256) void gemm1_k(
    const float* __restrict__ A, const _Float16* __restrict__ Bt,
    const float* __restrict__ b0, const float* __restrict__ b1,
    _Float16* __restrict__ out, int M, int K) {
  __shared__ _Float16 As[128 * 40];
  __shared__ _Float16 Bs[128 * 40];
  const int bid = blockIdx.x;
  const int mt = bid >> 2, nt = bid & 3;  // nt inner -> A-tile L2/L3 reuse
  const int m0 = mt * 128, n0 = nt * 128;
  const int t = threadIdx.x;
  const int lane = t & 63;
  const int wave = t >> 6;
  const int wm = wave >> 1, wn = wave & 1;
  const int lr = lane & 15, quad = lane >> 4;

  f32x4 acc[4][4] = {};

  for (int kt = 0; kt < K; kt += 32) {
#pragma unroll
    for (int i = 0; i < 2; i++) {
      int c = t + i * 256;
      int row = c >> 2, kc = (c & 3) * 8;
      int gr = m0 + row;
      if (gr > M - 1) gr = M - 1;
      const float* srcf = A + (size_t)gr * K + kt + kc;
      float4 f0 = ((const float4*)srcf)[0];
      float4 f1 = ((const float4*)srcf)[1];
      *(h8*)&As[row * 40 + kc] =
          h8{(_Float16)f0.x, (_Float16)f0.y, (_Float16)f0.z, (_Float16)f0.w,
             (_Float16)f1.x, (_Float16)f1.y, (_Float16)f1.z, (_Float16)f1.w};
      *(h8*)&Bs[row * 40 + kc] =
          *(const h8*)(Bt + (size_t)(n0 + row) * K + kt + kc);
    }
    __syncthreads();
    h8 af[4], bf[4];
#pragma unroll
    for (int i = 0; i < 4; i++)
      af[i] = *(h8*)&As[(wm * 64 + i * 16 + lr) * 40 + quad * 8];
#pragma unroll
    for (int j = 0; j < 4; j++)
      bf[j] = *(h8*)&Bs[(wn * 64 + j * 16 + lr) * 40 + quad * 8];
#pragma unroll
    for (int i = 0; i < 4; i++)
#pragma unroll
      for (int j = 0; j < 4; j++)
        acc[i][j] = __builtin_amdgcn_mfma_f32_16x16x32_f16(af[i], bf[j], acc[i][j], 0, 0, 0);
    __syncthreads();
  }

#pragma unroll
  for (int j = 0; j < 4; j++) {
    int gc = n0 + wn * 64 + j * 16 + lr;
    float bj = (gc < 256) ? b0[gc] : b1[gc - 256];
#pragma unroll
    for (int i = 0; i < 4; i++) {
#pragma unroll
      for (int r = 0; r < 4; r++) {
        int gr = m0 + wm * 64 + i * 16 + quad * 4 + r;
        if (gr < M) {
          float z = acc[i][j][r] + bj;
          float v = (gc < 256) ? elu_f(z) : fmaxf(z, 0.f);
          out[(size_t)gr * 512 + gc] = (_Float16)v;
        }
      }
    }
  }
}

// ---------------- GEMM2 + fused attention ----------------
// BM=128, N=128 (cols 0..63 mean, 64..127 var). 4 waves, each wave owns 32 rows
// (2 i-tiles) x all 8 j-tiles -> a lane holds mean col c (j<4) AND var col c
// (j+4) in registers -> attn computed in-register, packed h2 store to Mcat.
__global__ __launch_bounds__(256) void gemm2_k(
    const _Float16* __restrict__ A, const _Float16* __restrict__ Bt,
    const float* __restrict__ bm1, const float* __restrict__ bv1,
    uint32* __restrict__ Mcat, int M, int K) {
  __shared__ _Float16 As[128 * 40];
  __shared__ _Float16 Bs[128 * 40];
  const int m0 = blockIdx.x * 128;
  const int t = threadIdx.x;
  const int lane = t & 63;
  const int wave = t >> 6;
  const int lr = lane & 15, quad = lane >> 4;

  f32x4 acc[2][8] = {};

  for (int kt = 0; kt < K; kt += 32) {
#pragma unroll
    for (int i = 0; i < 2; i++) {
      int c = t + i * 256;
      int row = c >> 2, kc = (c & 3) * 8;
      int gr = m0 + row;
      if (gr > M - 1) gr = M - 1;
      *(h8*)&As[row * 40 + kc] = *(const h8*)(A + (size_t)gr * K + kt + kc);
      *(h8*)&Bs[row * 40 + kc] = *(const h8*)(Bt + (size_t)row * K + kt + kc);
    }
    __syncthreads();
    h8 af[2], bf[8];
#pragma unroll
    for (int i = 0; i < 2; i++)
      af[i] = *(h8*)&As[(wave * 32 + i * 16 + lr) * 40 + quad * 8];
#pragma unroll
    for (int j = 0; j < 8; j++)
      bf[j] = *(h8*)&Bs[(j * 16 + lr) * 40 + quad * 8];
#pragma unroll
    for (int i = 0; i < 2; i++)
#pragma unroll
      for (int j = 0; j < 8; j++)
        acc[i][j] = __builtin_amdgcn_mfma_f32_16x16x32_f16(af[i], bf[j], acc[i][j], 0, 0, 0);
    __syncthreads();
  }

#pragma unroll
  for (int jm = 0; jm < 4; jm++) {
    int c = jm * 16 + lr;                 // class col 0..63
    float bm = bm1[c], bv = bv1[c];
#pragma unroll
    for (int i = 0; i < 2; i++) {
#pragma unroll
      for (int r = 0; r < 4; r++) {
        int gr = m0 + wave * 32 + i * 16 + quad * 4 + r;
        if (gr < M) {
          float zm = acc[i][jm][r] + bm;
          float zv = acc[i][4 + jm][r] + bv;
          float m = elu_f(zm);
          float v = fmaxf(zv, 0.f) + 1e-6f;
          float a = __expf(-v);
          h2 pk;
          pk.x = (_Float16)(m * a);       // mean*attn
          pk.y = (_Float16)(v * a * a);   // var*attn^2
          Mcat[(size_t)gr * 64 + c] = __builtin_bit_cast(uint32, pk);
        }
      }
    }
  }
}

// ---------------- fused dual SpMM + reparam + log_softmax ----------------
// wave per node row, lane = class (CLS=64). 4-edge batches: one int4 csr load
// (16B-aligned via padded row starts) -> 4 independent dd + Mcat gathers.
__global__ __launch_bounds__(256) void spmm_final_k(
    const uint32* __restrict__ Mcat, const float2* __restrict__ dd,
    const int* __restrict__ row_start, const int* __restrict__ cnt,
    const int* __restrict__ csr, const float* __restrict__ sample,
    float* __restrict__ out, int n) {
  int wid = threadIdx.x >> 6, lane = threadIdx.x & 63;
  int r = blockIdx.x * 4 + wid;
  if (r >= n) return;
  float2 wr = dd[r];
  h2 self = __builtin_bit_cast(h2, Mcat[(size_t)r * 64 + lane]);
  float Sm = wr.x * (float)self.x;
  float Sv = wr.y * (float)self.y;
  int start = __builtin_amdgcn_readfirstlane(row_start[r]);
  int c = __builtin_amdgcn_readfirstlane(cnt[r]);
  int j = 0;
  for (; j + 4 <= c; j += 4) {
    int4 d4 = *(const int4*)(csr + start + j);
    float2 w0 = dd[d4.x];
    float2 w1 = dd[d4.y];
    float2 w2 = dd[d4.z];
    float2 w3 = dd[d4.w];
    h2 p0 = __builtin_bit_cast(h2, Mcat[(size_t)d4.x * 64 + lane]);
    h2 p1 = __builtin_bit_cast(h2, Mcat[(size_t)d4.y * 64 + lane]);
    h2 p2 = __builtin_bit_cast(h2, Mcat[(size_t)d4.z * 64 + lane]);
    h2 p3 = __builtin_bit_cast(h2, Mcat[(size_t)d4.w * 64 + lane]);
    Sm += w0.x * (float)p0.x; Sv += w0.y * (float)p0.y;
    Sm += w1.x * (float)p1.x; Sv += w1.y * (float)p1.y;
    Sm += w2.x * (float)p2.x; Sv += w2.y * (float)p2.y;
    Sm += w3.x * (float)p3.x; Sv += w3.y * (float)p3.y;
  }
  for (; j < c; j++) {
    int d = csr[start + j];
    float2 w = dd[d];
    h2 p = __builtin_bit_cast(h2, Mcat[(size_t)d * 64 + lane]);
    Sm += w.x * (float)p.x;
    Sv += w.y * (float)p.y;
  }
  float mean = wr.x * Sm;
  float var = wr.y * Sv;
  float o = mean + sample[(size_t)r * 64 + lane] * sqrtf(var);
  float mx = o;
#pragma unroll
  for (int off = 32; off; off >>= 1) mx = fmaxf(mx, __shfl_xor(mx, off, 64));
  float ex = __expf(o - mx);
  float s = ex;
#pragma unroll
  for (int off = 32; off; off >>= 1) s += __shfl_xor(s, off, 64);
  out[(size_t)r * 64 + lane] = o - mx - logf(s);
}

// ---------------- launch ----------------
extern "C" void kernel_launch(void* const* d_in, const int* in_sizes, int n_in,
                              void* d_out, int out_size, void* d_ws, size_t ws_size,
                              hipStream_t stream) {
  (void)n_in; (void)out_size; (void)ws_size;
  const float* x    = (const float*)d_in[0];
  const float* Wm0  = (const float*)d_in[1];
  const float* bm0  = (const float*)d_in[2];
  const float* Wv0  = (const float*)d_in[3];
  const float* bv0  = (const float*)d_in[4];
  const float* Wm1  = (const float*)d_in[5];
  const float* bm1  = (const float*)d_in[6];
  const float* Wv1  = (const float*)d_in[7];
  const float* bv1  = (const float*)d_in[8];
  const float* sample = (const float*)d_in[9];
  const int* esrc   = (const int*)d_in[10];
  const int* edst   = (const int*)d_in[11];
  float* out = (float*)d_out;

  const int N = in_sizes[0] / 512;
  const int E = in_sizes[10];

  uint8_t* p = (uint8_t*)d_ws;
  size_t off = 0;
  auto alloc = [&](size_t bytes) -> void* {
    void* r = p + off;
    off += (bytes + 255) & ~(size_t)255;
    return r;
  };
  _Float16* W1t  = (_Float16*)alloc((size_t)512 * 512 * 2);
  _Float16* W2t  = (_Float16*)alloc((size_t)128 * 512 * 2);
  _Float16* Hcat = (_Float16*)alloc((size_t)N * 512 * 2);
  uint32*   Mcat = (uint32*)alloc((size_t)N * 64 * 4);
  int*   cnt    = (int*)alloc((size_t)N * 4);
  float2* dd    = (float2*)alloc((size_t)N * 8);
  int*   rs     = (int*)alloc((size_t)N * 4);
  int*   cursor = (int*)alloc((size_t)N * 4);
  int*   bsum   = (int*)alloc(2048);
  int*   boff   = (int*)alloc(2048);
  int*   csr    = (int*)alloc((size_t)(E + 4 * N) * 4);  // padded rows

  hipMemsetAsync(cnt, 0, (size_t)N * 4, stream);

  const int nbN = (N + 255) / 256;
  const int nbE = (E + 255) / 256;

  prep_w_k<<<(512 * 512 + 255) / 256, 256, 0, stream>>>(Wm0, Wv0, Wm1, Wv1, W1t, W2t);
  deg_count_k<<<nbE, 256, 0, stream>>>(esrc, E, cnt);
  deg_fin_k<<<nbN, 256, 0, stream>>>(cnt, dd, N);
  scan1_k<<<nbN, 256, 0, stream>>>(cnt, rs, bsum, N);
  scan2_k<<<1, 512, 0, stream>>>(bsum, boff, nbN);
  scan3_k<<<nbN, 256, 0, stream>>>(rs, boff, cursor, N);
  scatter_k<<<nbE, 256, 0, stream>>>(esrc, edst, cursor, csr, E);

  const int mtiles = (N + 127) / 128;
  gemm1_k<<<mtiles * 4, 256, 0, stream>>>(x, W1t, bm0, bv0, Hcat, N, 512);
  gemm2_k<<<mtiles, 256, 0, stream>>>(Hcat, W2t, bm1, bv1, Mcat, N, 512);
  spmm_final_k<<<(N + 3) / 4, 256, 0, stream>>>(Mcat, dd, rs, cnt, csr, sample, out, N);
}